// Round 1
// baseline (431.629 us; speedup 1.0000x reference)
//
#include <hip/hip_runtime.h>

// Complex FIR, taps=11, SAME padding, stride 1.
// X: (BATCH, N, 2) fp32 interleaved (re, im). phi: (TAPS, 2, 1).
// out[b,n] = sum_k X[b, n-5+k] * phi[k]  (complex MAC, zero-padded edges)
//
// V2: SoA LDS (s_re/s_im) + adjacent-pair outputs per thread:
//  - global loads  : float4 (2 complex / 16 B per lane)   [was float2]
//  - global stores : float4 (2 complex / 16 B per lane)   [was float2]
//  - LDS reads     : 14 ds_read_b64 per output pair        [was 22]
//  - LDS lane stride stays 8 B (benign 2-way) because re/im are split.
// Tile = 2048 complex/block; pad = 6 (even) so no float4 straddles a row
// boundary (N even, pad even -> pairs are all-in or all-out).

constexpr int N_SAMP  = 262144;
constexpr int BATCH   = 128;
constexpr int TAPS    = 11;
constexpr int BLOCK   = 256;
constexpr int PAIRS   = 4;                    // output pairs per thread
constexpr int TILE    = BLOCK * PAIRS * 2;    // 2048 complex per block
constexpr int PAD     = 6;                    // even left pad >= halo(5)
constexpr int N_SLOTS = TILE / 2 + PAD;       // float4 staging slots = 1030
constexpr int SMEM_N  = 2 * N_SLOTS;          // floats per component = 2060

__global__ __launch_bounds__(BLOCK)
void fir_complex_kernel(const float2* __restrict__ X,
                        const float*  __restrict__ phi,
                        float2*       __restrict__ out)
{
    __shared__ __align__(16) float s_re[SMEM_N];
    __shared__ __align__(16) float s_im[SMEM_N];

    const int t          = threadIdx.x;
    const int tile_start = blockIdx.x * TILE;
    const long long row  = (long long)blockIdx.y * N_SAMP;

    // Taps: uniform loads, held in registers.
    float pr[TAPS], pi[TAPS];
#pragma unroll
    for (int k = 0; k < TAPS; ++k) {
        pr[k] = phi[2 * k + 0];
        pi[k] = phi[2 * k + 1];
    }

    // ---- Stage tile + halo into SoA LDS via float4 global loads ----
    // Staged complex range: [tile_start - PAD, tile_start - PAD + 2*N_SLOTS)
    //                     = [ts-6, ts+2054)  (covers outputs' [ts-5, ts+2052])
    const float4* __restrict__ X4 = reinterpret_cast<const float4*>(X);
    const int g0 = tile_start - PAD;          // even
#pragma unroll
    for (int r = 0; r < (N_SLOTS + BLOCK - 1) / BLOCK; ++r) {
        const int i4 = r * BLOCK + t;
        if (i4 < N_SLOTS) {
            const int g = g0 + 2 * i4;        // even complex index
            float4 v = make_float4(0.f, 0.f, 0.f, 0.f);
            // g even, N even  =>  g in range implies g+1 in range too.
            if ((unsigned)g < (unsigned)N_SAMP)
                v = X4[(row + g) >> 1];
            *reinterpret_cast<float2*>(&s_re[2 * i4]) = make_float2(v.x, v.z);
            *reinterpret_cast<float2*>(&s_im[2 * i4]) = make_float2(v.y, v.w);
        }
    }
    __syncthreads();

    // ---- Compute: each thread does PAIRS adjacent-output pairs ----
    // LDS float index of complex m is (m - ts + PAD); output pair at relative
    // l (even) consumes window s[l+1 .. l+12]; we read the aligned [l, l+13].
    float4* __restrict__ out4 = reinterpret_cast<float4*>(out);
#pragma unroll
    for (int j = 0; j < PAIRS; ++j) {
        const int l = 2 * t + j * (2 * BLOCK);   // even, 0..2046

        float wre[14], wim[14];
#pragma unroll
        for (int q = 0; q < 7; ++q) {
            const float2 a = *reinterpret_cast<const float2*>(&s_re[l + 2 * q]);
            const float2 b = *reinterpret_cast<const float2*>(&s_im[l + 2 * q]);
            wre[2 * q]     = a.x;
            wre[2 * q + 1] = a.y;
            wim[2 * q]     = b.x;
            wim[2 * q + 1] = b.y;
        }

        float r0 = 0.f, i0 = 0.f, r1 = 0.f, i1 = 0.f;
#pragma unroll
        for (int k = 0; k < TAPS; ++k) {
            const float xr0 = wre[k + 1], xi0 = wim[k + 1];
            const float xr1 = wre[k + 2], xi1 = wim[k + 2];
            r0 = fmaf(xr0,  pr[k], r0);
            r0 = fmaf(-xi0, pi[k], r0);
            i0 = fmaf(xr0,  pi[k], i0);
            i0 = fmaf(xi0,  pr[k], i0);
            r1 = fmaf(xr1,  pr[k], r1);
            r1 = fmaf(-xi1, pi[k], r1);
            i1 = fmaf(xr1,  pi[k], i1);
            i1 = fmaf(xi1,  pr[k], i1);
        }

        // Coalesced 16 B/lane store: lanes t, t+1 are 16 B apart.
        out4[(row + tile_start + l) >> 1] = make_float4(r0, i0, r1, i1);
    }
}

extern "C" void kernel_launch(void* const* d_in, const int* in_sizes, int n_in,
                              void* d_out, int out_size, void* d_ws, size_t ws_size,
                              hipStream_t stream)
{
    const float2* X   = (const float2*)d_in[0];
    const float*  phi = (const float*)d_in[1];
    float2*       out = (float2*)d_out;

    dim3 grid(N_SAMP / TILE, BATCH);   // 128 x 128 = 16384 blocks
    fir_complex_kernel<<<grid, BLOCK, 0, stream>>>(X, phi, out);
}